// Round 11
// baseline (155.104 us; speedup 1.0000x reference)
//
#include <hip/hip_runtime.h>
#include <hip/hip_fp16.h>

#define NN 50000
#define NE 800000

// bucket sort: bucket = dst >> 8 (256 dsts per bucket)
#define NBK 196                    // ceil(50000/256)
#define BSH 8
#define BMASK 255
#define SCAP 5120                  // >= max bucket population (mean 4082, +16 sigma)
#define CHUNK 2048                 // edges per sortA block
#define NBLK_A ((NE + CHUNK - 1) / CHUNK)   // 391
#define NBLK_P ((NN + 63) / 64)             // 782
#define GPAD 4                     // gcur stride = 16 ints = 64 B (1 line per counter)
#define AGG_BLOCKS 1024            // grid-stride aggregation: 1024 x 8 waves = 8192 waves

typedef _Float16 f16x8 __attribute__((ext_vector_type(8)));
typedef float f32x4 __attribute__((ext_vector_type(4)));

// ---------------- K1: init gcur + convert/transpose weights ----------------
__global__ __launch_bounds__(256) void init_k(const float* __restrict__ W1,
                                              const float* __restrict__ W2,
                                              __half* __restrict__ w1t,
                                              __half* __restrict__ w2t,
                                              int* __restrict__ gcur) {
    const int i = blockIdx.x * 256 + threadIdx.x;   // 64 blocks = 16384 = 128*128
    {
        const int k = i >> 7, n = i & 127;
        w1t[n * 128 + k] = __float2half(W1[i]);
    }
    if (i < 128 * 64) {
        const int k = i >> 6, n = i & 63;
        w2t[n * 128 + k] = __float2half(W2[i]);
    }
    if (i < NBK) gcur[i << GPAD] = 0;
}

// ---------------- K2: fused sortA (bucket binning) + proj1 (MFMA) ----------------
__global__ __launch_bounds__(256) void sortA_proj1_k(const int* __restrict__ src,
                                                     const int* __restrict__ dst,
                                                     const float* __restrict__ wE,
                                                     int* __restrict__ gcur,
                                                     int2* __restrict__ stage,
                                                     const float* __restrict__ x,
                                                     const __half* __restrict__ w1t,
                                                     const float* __restrict__ al1,
                                                     const float* __restrict__ ar1,
                                                     __half* __restrict__ h1h,
                                                     float* __restrict__ el1,
                                                     float* __restrict__ er1) {
    const int t = threadIdx.x;
    if (blockIdx.x < NBLK_A) {
        // ---- sortA ----
        __shared__ int hcnt[NBK], lexcl[NBK], lcur[NBK], gbase[NBK];
        __shared__ int wsum[4];
        __shared__ int2 lbuf[CHUNK];
        const int e0 = blockIdx.x * CHUNK;
        const int ne = min(CHUNK, NE - e0);
        if (t < NBK) { hcnt[t] = 0; lcur[t] = 0; }
        __syncthreads();
        for (int i = t; i < ne; i += 256) atomicAdd(&hcnt[dst[e0 + i] >> BSH], 1);
        __syncthreads();
        {
            const int lane = t & 63, wid = t >> 6;
            const int v = (t < NBK) ? hcnt[t] : 0;
            int s = v;
            #pragma unroll
            for (int off = 1; off < 64; off <<= 1) {
                int u = __shfl_up(s, off, 64);
                if (lane >= off) s += u;
            }
            if (lane == 63) wsum[wid] = s;
            __syncthreads();
            int add = 0;
            for (int w = 0; w < wid; w++) add += wsum[w];
            if (t < NBK) lexcl[t] = s - v + add;
        }
        __syncthreads();
        if (t < NBK && hcnt[t] > 0) gbase[t] = atomicAdd(&gcur[t << GPAD], hcnt[t]);
        __syncthreads();
        for (int i = t; i < ne; i += 256) {
            const int d = dst[e0 + i];
            const int b = d >> BSH;
            const int r = atomicAdd(&lcur[b], 1);
            lbuf[lexcl[b] + r] = make_int2((src[e0 + i] & 0xFFFF) | ((d & BMASK) << 16),
                                           __float_as_int(wE[e0 + i]));
        }
        __syncthreads();
        const int wv = t >> 6, lane = t & 63;
        for (int b = wv; b < NBK; b += 4) {
            const int cnt = hcnt[b];
            if (cnt == 0) continue;
            const int lo = lexcl[b];
            int2* dp = stage + (size_t)b * SCAP + gbase[b];
            for (int j = lane; j < cnt; j += 64) dp[j] = lbuf[lo + j];
        }
    } else {
        // ---- proj1 (MFMA) ----
        const int bid = blockIdx.x - NBLK_A;
        const int l = t & 63, wv = t >> 6;
        const int rbase = bid * 64 + wv * 16;
        const int cl = l & 15, kg = l >> 4;
        const int arow = rbase + cl;
        const float* xrow = x + (size_t)(arow < NN ? arow : NN - 1) * 128;
        f16x8 afrag[4];
        #pragma unroll
        for (int ks = 0; ks < 4; ks++) {
            const float4 u0 = *(const float4*)(xrow + ks * 32 + kg * 8);
            const float4 u1 = *(const float4*)(xrow + ks * 32 + kg * 8 + 4);
            f16x8 a;
            a[0] = (_Float16)u0.x; a[1] = (_Float16)u0.y; a[2] = (_Float16)u0.z; a[3] = (_Float16)u0.w;
            a[4] = (_Float16)u1.x; a[5] = (_Float16)u1.y; a[6] = (_Float16)u1.z; a[7] = (_Float16)u1.w;
            afrag[ks] = a;
        }
        f32x4 acc[8];
        #pragma unroll
        for (int nt = 0; nt < 8; nt++) { acc[nt][0]=0.f; acc[nt][1]=0.f; acc[nt][2]=0.f; acc[nt][3]=0.f; }
        #pragma unroll
        for (int nt = 0; nt < 8; nt++) {
            const f16x8* bp = (const f16x8*)(w1t + (size_t)(nt * 16 + cl) * 128 + kg * 8);
            #pragma unroll
            for (int ks = 0; ks < 4; ks++)
                acc[nt] = __builtin_amdgcn_mfma_f32_16x16x32_f16(afrag[ks], bp[ks * 4], acc[nt], 0, 0, 0);
        }
        const int orow0 = rbase + kg * 4;
        #pragma unroll
        for (int nt = 0; nt < 8; nt++) {
            const int col = nt * 16 + cl;
            const float alc = al1[col], arc = ar1[col];
            #pragma unroll
            for (int r = 0; r < 4; r++) {
                const float v = acc[nt][r];
                const int orow = orow0 + r;
                const bool ok = (orow < NN);
                if (ok) h1h[(size_t)orow * 128 + col] = __float2half(v);
                float pe = v * alc, pr = v * arc;
                #pragma unroll
                for (int m = 1; m < 16; m <<= 1) {
                    pe += __shfl_xor(pe, m, 64);
                    pr += __shfl_xor(pr, m, 64);
                }
                if (ok && cl == 0) {
                    el1[(size_t)orow * 8 + nt] = pe;
                    er1[(size_t)orow * 8 + nt] = pr;
                }
            }
        }
    }
}

// ---------------- K3: sortB — per-bucket histogram -> offs, scatter to csr ----------------
__global__ __launch_bounds__(1024) void sortB_k(const int* __restrict__ gcur,
                                                const int2* __restrict__ stage,
                                                int* __restrict__ offs,
                                                unsigned int* __restrict__ csr) {
    __shared__ int cnt[256], cur[256], gall[NBK];
    __shared__ int wsum[4];
    __shared__ int sbase;
    const int b = blockIdx.x, t = threadIdx.x;
    if (t < NBK) gall[t] = gcur[t << GPAD];
    if (t < 256) cnt[t] = 0;
    __syncthreads();
    const int nb = gall[b];
    if (t < 64) {   // wave 0: base = sum gall[0..b)
        int part = 0;
        for (int i = t; i < b; i += 64) part += gall[i];
        #pragma unroll
        for (int m = 1; m < 64; m <<= 1) part += __shfl_xor(part, m, 64);
        if (t == 0) sbase = part;
    }
    const int2* sp = stage + (size_t)b * SCAP;
    for (int i = t; i < nb; i += 1024) atomicAdd(&cnt[(sp[i].x >> 16) & BMASK], 1);
    __syncthreads();
    const int base = sbase;
    const int dlo = b << BSH;
    {   // exclusive scan of cnt[0..256) by threads 0..255
        const int lane = t & 63, wid = t >> 6;
        const int v = (t < 256) ? cnt[t] : 0;
        int s = v;
        #pragma unroll
        for (int off = 1; off < 64; off <<= 1) {
            int u = __shfl_up(s, off, 64);
            if (lane >= off) s += u;
        }
        if (t < 256 && lane == 63) wsum[wid] = s;
        __syncthreads();
        if (t < 256) {
            int add = 0;
            for (int w = 0; w < wid; w++) add += wsum[w];
            const int excl = s - v + add;
            cur[t] = excl;
            if (dlo + t < NN) offs[dlo + t] = base + excl;
        }
        if (b == NBK - 1 && t == 0) offs[NN] = base + nb;
    }
    __syncthreads();
    for (int i = t; i < nb; i += 1024) {
        const int2 pr = sp[i];
        const int dloc = (pr.x >> 16) & BMASK;
        const int sv = pr.x & 0xFFFF;
        const int r = atomicAdd(&cur[dloc], 1);
        const __half hw = __float2half(__int_as_float(pr.y));
        csr[base + r] = (unsigned int)sv | ((unsigned int)__half_as_ushort(hw) << 16);
    }
}

// ---------------- K4: Layer 1 aggregation — grid-stride, 8 waves/block, 1 node/wave ----------------
// logits: head h=l&7, eb=l>>3; lane's edges E'=eb+8k' (k'=0..3), pw kept in flat pwv[k'].
// values: dim-group g=l&15 (head hg=g>>1), es=l>>4; lane's edges E=es+4k (k=0..7).
//   pw[E][hg] lives in lane ((E&7)<<3)|hg = ((es+4*(k&1))<<3)|hg, slot E>>3 = k>>1.
__global__ __launch_bounds__(512) void agg1_k(const int* __restrict__ offs,
                                              const unsigned int* __restrict__ csr,
                                              const __half* __restrict__ h1h,
                                              const float* __restrict__ el1,
                                              const float* __restrict__ er1,
                                              const float* __restrict__ b1,
                                              __half* __restrict__ h2in_h) {
    const int t = threadIdx.x, wid = t >> 6, l = t & 63;
    const int h = l & 7, eb = l >> 3;
    const int g = l & 15, es = l >> 4, hg = g >> 1;
    const float4* hp4 = (const float4*)h1h;
    const float4* b4 = (const float4*)b1;
    const float4 bb0 = b4[g * 2], bb1 = b4[g * 2 + 1];

    for (int n = blockIdx.x * 8 + wid; n < NN; n += AGG_BLOCKS * 8) {
        const int beg = offs[n], deg = offs[n + 1] - beg;
        const float er_h = er1[(size_t)n * 8 + h];
        float z_lane = 0.f;
        float acc[8];
        #pragma unroll
        for (int j = 0; j < 8; j++) acc[j] = 0.f;

        int pr = 0;
        if (l < 32 && l < deg) pr = (int)csr[beg + l];
        for (int base = 0; base < deg; base += 32) {
            // prefetch next tile's csr
            int prn = 0;
            const int nbase = base + 32;
            if (nbase < deg && l < 32 && nbase + l < deg) prn = (int)csr[beg + nbase + l];
            // logits: this lane's 4 edges (eb+8k') at head h
            float pwv[4];
            #pragma unroll
            for (int k = 0; k < 4; k++) {
                const unsigned int pre = (unsigned int)__shfl(pr, eb + 8 * k, 64);
                float lg = -1e30f;
                if (base + eb + 8 * k < deg) {
                    const float v = el1[(size_t)(pre & 0xFFFF) * 8 + h] + er_h;
                    lg = v > 0.f ? v : 0.2f * v;
                }
                const float p = __expf(lg);    // 0 for padded slots
                z_lane += p;
                pwv[k] = p * __half2float(__ushort_as_half((unsigned short)(pre >> 16)));
            }
            // values: 8 edges E = es+4k
            int sv[8];
            float pp[8];
            #pragma unroll
            for (int k = 0; k < 8; k++) sv[k] = __shfl(pr, es + 4 * k, 64) & 0xFFFF;
            #pragma unroll
            for (int k = 0; k < 8; k++) {
                const int slane = ((es + 4 * (k & 1)) << 3) | hg;
                pp[k] = __shfl(pwv[k >> 1], slane, 64);
            }
            float4 vv[8];
            #pragma unroll
            for (int k = 0; k < 8; k++) vv[k] = hp4[(size_t)sv[k] * 16 + g];
            #pragma unroll
            for (int k = 0; k < 8; k++) {
                #pragma unroll
                for (int q = 0; q < 4; q++) {
                    const float2 f = __half22float2(((const __half2*)&vv[k])[q]);
                    acc[2 * q]     = fmaf(pp[k], f.x, acc[2 * q]);
                    acc[2 * q + 1] = fmaf(pp[k], f.y, acc[2 * q + 1]);
                }
            }
            pr = prn;
        }
        // z: reduce over eb (bits 3,4,5)
        z_lane += __shfl_xor(z_lane, 8, 64);
        z_lane += __shfl_xor(z_lane, 16, 64);
        z_lane += __shfl_xor(z_lane, 32, 64);
        // acc: reduce over es (bits 4,5)
        #pragma unroll
        for (int j = 0; j < 8; j++) {
            acc[j] += __shfl_xor(acc[j], 16, 64);
            acc[j] += __shfl_xor(acc[j], 32, 64);
        }
        const float zg = __shfl(z_lane, hg, 64);   // lane hg: eb=0, h=hg
        if (l < 16) {
            const float inv = (deg > 0) ? 1.f / zg : 0.f;
            __half hv[8];
            hv[0] = __float2half(fmaxf(acc[0] * inv + bb0.x, 0.f));
            hv[1] = __float2half(fmaxf(acc[1] * inv + bb0.y, 0.f));
            hv[2] = __float2half(fmaxf(acc[2] * inv + bb0.z, 0.f));
            hv[3] = __float2half(fmaxf(acc[3] * inv + bb0.w, 0.f));
            hv[4] = __float2half(fmaxf(acc[4] * inv + bb1.x, 0.f));
            hv[5] = __float2half(fmaxf(acc[5] * inv + bb1.y, 0.f));
            hv[6] = __float2half(fmaxf(acc[6] * inv + bb1.z, 0.f));
            hv[7] = __float2half(fmaxf(acc[7] * inv + bb1.w, 0.f));
            *(int4*)(h2in_h + (size_t)n * 128 + g * 8) = *(const int4*)hv;
        }
    }
}

// ---------------- K5: Layer 2 projection (MFMA) ----------------
__global__ __launch_bounds__(256) void proj2_k(const __half* __restrict__ xh,
                                               const __half* __restrict__ w2t,
                                               const float* __restrict__ al2,
                                               const float* __restrict__ ar2,
                                               __half* __restrict__ h2h,
                                               float* __restrict__ el2,
                                               float* __restrict__ er2) {
    const int t = threadIdx.x, l = t & 63, wv = t >> 6;
    const int rbase = blockIdx.x * 64 + wv * 16;
    const int cl = l & 15, kg = l >> 4;
    const int arow = rbase + cl;
    const __half* xrow = xh + (size_t)(arow < NN ? arow : NN - 1) * 128;
    f16x8 afrag[4];
    #pragma unroll
    for (int ks = 0; ks < 4; ks++)
        afrag[ks] = *(const f16x8*)(xrow + ks * 32 + kg * 8);
    f32x4 acc[4];
    #pragma unroll
    for (int nt = 0; nt < 4; nt++) { acc[nt][0]=0.f; acc[nt][1]=0.f; acc[nt][2]=0.f; acc[nt][3]=0.f; }
    #pragma unroll
    for (int nt = 0; nt < 4; nt++) {
        const f16x8* bp = (const f16x8*)(w2t + (size_t)(nt * 16 + cl) * 128 + kg * 8);
        #pragma unroll
        for (int ks = 0; ks < 4; ks++)
            acc[nt] = __builtin_amdgcn_mfma_f32_16x16x32_f16(afrag[ks], bp[ks * 4], acc[nt], 0, 0, 0);
    }
    const int orow0 = rbase + kg * 4;
    float pe[4] = {0.f, 0.f, 0.f, 0.f}, pr[4] = {0.f, 0.f, 0.f, 0.f};
    #pragma unroll
    for (int nt = 0; nt < 4; nt++) {
        const int col = nt * 16 + cl;
        const float alc = al2[col], arc = ar2[col];
        #pragma unroll
        for (int r = 0; r < 4; r++) {
            const float v = acc[nt][r];
            const int orow = orow0 + r;
            if (orow < NN) h2h[(size_t)orow * 64 + col] = __float2half(v);
            pe[r] = fmaf(v, alc, pe[r]);
            pr[r] = fmaf(v, arc, pr[r]);
        }
    }
    #pragma unroll
    for (int r = 0; r < 4; r++) {
        #pragma unroll
        for (int m = 1; m < 16; m <<= 1) {
            pe[r] += __shfl_xor(pe[r], m, 64);
            pr[r] += __shfl_xor(pr[r], m, 64);
        }
        const int orow = orow0 + r;
        if (cl == 0 && orow < NN) { el2[orow] = pe[r]; er2[orow] = pr[r]; }
    }
}

// ---------------- K6: Layer 2 aggregation — grid-stride, 8 waves/block ----------------
// logits: lane l<32 owns edge l. values: g=l&7 (8 dims), es=l>>3 (0..7), edges es+8k (k=0..3)
__global__ __launch_bounds__(512) void agg2_k(const int* __restrict__ offs,
                                              const unsigned int* __restrict__ csr,
                                              const __half* __restrict__ h2h,
                                              const float* __restrict__ el2,
                                              const float* __restrict__ er2,
                                              const float* __restrict__ b2,
                                              float* __restrict__ out) {
    const int t = threadIdx.x, wid = t >> 6, l = t & 63;
    const int g = l & 7, es = l >> 3;
    const float4* hp4 = (const float4*)h2h;
    const float4* b4 = (const float4*)b2;
    const float4 bb0 = b4[g * 2], bb1 = b4[g * 2 + 1];

    for (int n = blockIdx.x * 8 + wid; n < NN; n += AGG_BLOCKS * 8) {
        const int beg = offs[n], deg = offs[n + 1] - beg;
        const float erd = er2[n];
        float z_lane = 0.f;
        float acc[8];
        #pragma unroll
        for (int j = 0; j < 8; j++) acc[j] = 0.f;

        int pr = 0;
        if (l < 32 && l < deg) pr = (int)csr[beg + l];
        for (int base = 0; base < deg; base += 32) {
            int prn = 0;
            const int nbase = base + 32;
            if (nbase < deg && l < 32 && nbase + l < deg) prn = (int)csr[beg + nbase + l];
            float pw = 0.f;
            if (l < 32 && base + l < deg) {
                const float v = el2[(unsigned int)pr & 0xFFFF] + erd;
                const float lg = v > 0.f ? v : 0.2f * v;
                const float p = __expf(lg);
                z_lane += p;
                pw = p * __half2float(__ushort_as_half((unsigned short)((unsigned int)pr >> 16)));
            }
            int sv[4];
            float pp[4];
            #pragma unroll
            for (int k = 0; k < 4; k++) {
                sv[k] = __shfl(pr, es + 8 * k, 64) & 0xFFFF;
                pp[k] = __shfl(pw, es + 8 * k, 64);
            }
            float4 vv[4];
            #pragma unroll
            for (int k = 0; k < 4; k++) vv[k] = hp4[(size_t)sv[k] * 8 + g];
            #pragma unroll
            for (int k = 0; k < 4; k++) {
                #pragma unroll
                for (int q = 0; q < 4; q++) {
                    const float2 f = __half22float2(((const __half2*)&vv[k])[q]);
                    acc[2 * q]     = fmaf(pp[k], f.x, acc[2 * q]);
                    acc[2 * q + 1] = fmaf(pp[k], f.y, acc[2 * q + 1]);
                }
            }
            pr = prn;
        }
        // z: full butterfly (lanes >=32 contribute 0)
        z_lane += __shfl_xor(z_lane, 1, 64);
        z_lane += __shfl_xor(z_lane, 2, 64);
        z_lane += __shfl_xor(z_lane, 4, 64);
        z_lane += __shfl_xor(z_lane, 8, 64);
        z_lane += __shfl_xor(z_lane, 16, 64);
        z_lane += __shfl_xor(z_lane, 32, 64);
        // acc: reduce over es (bits 3,4,5)
        #pragma unroll
        for (int j = 0; j < 8; j++) {
            acc[j] += __shfl_xor(acc[j], 8, 64);
            acc[j] += __shfl_xor(acc[j], 16, 64);
            acc[j] += __shfl_xor(acc[j], 32, 64);
        }
        if (l < 8) {
            const float inv = (deg > 0) ? 1.f / z_lane : 0.f;
            float4 o0, o1;
            o0.x = acc[0] * inv + bb0.x;
            o0.y = acc[1] * inv + bb0.y;
            o0.z = acc[2] * inv + bb0.z;
            o0.w = acc[3] * inv + bb0.w;
            o1.x = acc[4] * inv + bb1.x;
            o1.y = acc[5] * inv + bb1.y;
            o1.z = acc[6] * inv + bb1.z;
            o1.w = acc[7] * inv + bb1.w;
            float4* op = (float4*)(out + (size_t)n * 64 + g * 8);
            op[0] = o0; op[1] = o1;
        }
    }
}

// ---------------- host ----------------

extern "C" void kernel_launch(void* const* d_in, const int* in_sizes, int n_in,
                              void* d_out, int out_size, void* d_ws, size_t ws_size,
                              hipStream_t stream) {
    const float* feat = (const float*)d_in[0];
    const int*   srcv = (const int*)d_in[1];
    const int*   dstv = (const int*)d_in[2];
    const float* wE   = (const float*)d_in[3];
    const float* W1   = (const float*)d_in[4];
    const float* al1  = (const float*)d_in[5];
    const float* ar1  = (const float*)d_in[6];
    const float* b1   = (const float*)d_in[7];
    const float* W2   = (const float*)d_in[8];
    const float* al2  = (const float*)d_in[9];
    const float* ar2  = (const float*)d_in[10];
    const float* b2   = (const float*)d_in[11];
    float* out = (float*)d_out;

    char* ws = (char*)d_ws;
    size_t off = 0;
    auto take = [&](size_t bytes) -> char* {
        char* pp = ws + off;
        off = (off + bytes + 255) & ~(size_t)255;
        return pp;
    };
    __half* h1h   = (__half*)take((size_t)NN * 128 * 2);
    __half* h2h   = (__half*)take((size_t)NN * 64 * 2);
    __half* h2in_h= (__half*)take((size_t)NN * 128 * 2);   // 12.8 MB; first ~8 MB aliased as sort staging
    float* el1  = (float*)take((size_t)NN * 8 * 4);
    float* er1  = (float*)take((size_t)NN * 8 * 4);
    float* el2  = (float*)take((size_t)NN * 4);
    float* er2  = (float*)take((size_t)NN * 4);
    int* offs   = (int*)take((size_t)(NN + 1) * 4);
    unsigned int* csr = (unsigned int*)take((size_t)NE * 4);
    int* gcur   = (int*)take((size_t)(NBK << GPAD) * 4);
    __half* w1t = (__half*)take((size_t)128 * 128 * 2);
    __half* w2t = (__half*)take((size_t)64 * 128 * 2);
    int2* stage = (int2*)h2in_h;   // NBK*SCAP*8 = 8.03 MB, consumed (sortB) before agg1 writes h2in_h

    init_k<<<64, 256, 0, stream>>>(W1, W2, w1t, w2t, gcur);
    sortA_proj1_k<<<NBLK_A + NBLK_P, 256, 0, stream>>>(srcv, dstv, wE, gcur, stage,
                                                       feat, w1t, al1, ar1, h1h, el1, er1);
    sortB_k<<<NBK, 1024, 0, stream>>>(gcur, stage, offs, csr);
    agg1_k<<<AGG_BLOCKS, 512, 0, stream>>>(offs, csr, h1h, el1, er1, b1, h2in_h);
    proj2_k<<<(NN + 63) / 64, 256, 0, stream>>>(h2in_h, w2t, al2, ar2, h2h, el2, er2);
    agg2_k<<<AGG_BLOCKS, 512, 0, stream>>>(offs, csr, h2h, el2, er2, b2, out);
}

// Round 12
// 138.006 us; speedup vs baseline: 1.1239x; 1.1239x over previous
//
#include <hip/hip_runtime.h>
#include <hip/hip_fp16.h>

#define NN 50000
#define NE 800000

// bucket sort: bucket = dst >> 8 (256 dsts per bucket)
#define NBK 196                    // ceil(50000/256)
#define BSH 8
#define BMASK 255
#define SCAP 5120                  // >= max bucket population (mean 4082, +16 sigma)
#define CHUNK 2048                 // edges per sortA block
#define NBLK_A ((NE + CHUNK - 1) / CHUNK)   // 391
#define NBLK_P ((NN + 63) / 64)             // 782
#define GPAD 4                     // gcur stride = 16 ints = 64 B (1 line per counter)

typedef _Float16 f16x8 __attribute__((ext_vector_type(8)));
typedef float f32x4 __attribute__((ext_vector_type(4)));

// ---------------- K1: init gcur + convert/transpose weights ----------------
__global__ __launch_bounds__(256) void init_k(const float* __restrict__ W1,
                                              const float* __restrict__ W2,
                                              __half* __restrict__ w1t,
                                              __half* __restrict__ w2t,
                                              int* __restrict__ gcur) {
    const int i = blockIdx.x * 256 + threadIdx.x;   // 64 blocks = 16384 = 128*128
    {
        const int k = i >> 7, n = i & 127;
        w1t[n * 128 + k] = __float2half(W1[i]);
    }
    if (i < 128 * 64) {
        const int k = i >> 6, n = i & 63;
        w2t[n * 128 + k] = __float2half(W2[i]);
    }
    if (i < NBK) gcur[i << GPAD] = 0;
}

// ---------------- K2: fused sortA (bucket binning, flat flush) + proj1 (MFMA) ----------------
__global__ __launch_bounds__(256) void sortA_proj1_k(const int* __restrict__ src,
                                                     const int* __restrict__ dst,
                                                     const float* __restrict__ wE,
                                                     int* __restrict__ gcur,
                                                     int2* __restrict__ stage,
                                                     const float* __restrict__ x,
                                                     const __half* __restrict__ w1t,
                                                     const float* __restrict__ al1,
                                                     const float* __restrict__ ar1,
                                                     __half* __restrict__ h1h,
                                                     float* __restrict__ el1,
                                                     float* __restrict__ er1) {
    const int t = threadIdx.x;
    if (blockIdx.x < NBLK_A) {
        // ---- sortA ----
        __shared__ int hcnt[NBK], lexcl[NBK], lcur[NBK], gbase[NBK];
        __shared__ int wsum[4];
        __shared__ int2 lbuf[CHUNK];
        const int e0 = blockIdx.x * CHUNK;
        const int ne = min(CHUNK, NE - e0);
        if (t < NBK) { hcnt[t] = 0; lcur[t] = 0; }
        __syncthreads();
        for (int i = t; i < ne; i += 256) atomicAdd(&hcnt[dst[e0 + i] >> BSH], 1);
        __syncthreads();
        {
            const int lane = t & 63, wid = t >> 6;
            const int v = (t < NBK) ? hcnt[t] : 0;
            int s = v;
            #pragma unroll
            for (int off = 1; off < 64; off <<= 1) {
                int u = __shfl_up(s, off, 64);
                if (lane >= off) s += u;
            }
            if (lane == 63) wsum[wid] = s;
            __syncthreads();
            int add = 0;
            for (int w = 0; w < wid; w++) add += wsum[w];
            if (t < NBK) lexcl[t] = s - v + add;
        }
        __syncthreads();
        if (t < NBK && hcnt[t] > 0) gbase[t] = atomicAdd(&gcur[t << GPAD], hcnt[t]);
        __syncthreads();
        for (int i = t; i < ne; i += 256) {
            const int d = dst[e0 + i];
            const int b = d >> BSH;
            const int r = atomicAdd(&lcur[b], 1);
            // payload: src(16) | dloc(8)<<16 | bucket(8)<<24 ; sortB masks what it needs
            lbuf[lexcl[b] + r] = make_int2((src[e0 + i] & 0xFFFF) | ((d & BMASK) << 16) | (b << 24),
                                           __float_as_int(wE[e0 + i]));
        }
        __syncthreads();
        // flat parallel flush: every thread moves elements, bucket read from payload byte
        for (int i = t; i < ne; i += 256) {
            const int2 v = lbuf[i];
            const int b = (unsigned int)v.x >> 24;
            const int pos = gbase[b] + (i - lexcl[b]);
            stage[(size_t)b * SCAP + pos] = v;
        }
    } else {
        // ---- proj1 (MFMA) ----
        const int bid = blockIdx.x - NBLK_A;
        const int l = t & 63, wv = t >> 6;
        const int rbase = bid * 64 + wv * 16;
        const int cl = l & 15, kg = l >> 4;
        const int arow = rbase + cl;
        const float* xrow = x + (size_t)(arow < NN ? arow : NN - 1) * 128;
        f16x8 afrag[4];
        #pragma unroll
        for (int ks = 0; ks < 4; ks++) {
            const float4 u0 = *(const float4*)(xrow + ks * 32 + kg * 8);
            const float4 u1 = *(const float4*)(xrow + ks * 32 + kg * 8 + 4);
            f16x8 a;
            a[0] = (_Float16)u0.x; a[1] = (_Float16)u0.y; a[2] = (_Float16)u0.z; a[3] = (_Float16)u0.w;
            a[4] = (_Float16)u1.x; a[5] = (_Float16)u1.y; a[6] = (_Float16)u1.z; a[7] = (_Float16)u1.w;
            afrag[ks] = a;
        }
        f32x4 acc[8];
        #pragma unroll
        for (int nt = 0; nt < 8; nt++) { acc[nt][0]=0.f; acc[nt][1]=0.f; acc[nt][2]=0.f; acc[nt][3]=0.f; }
        #pragma unroll
        for (int nt = 0; nt < 8; nt++) {
            const f16x8* bp = (const f16x8*)(w1t + (size_t)(nt * 16 + cl) * 128 + kg * 8);
            #pragma unroll
            for (int ks = 0; ks < 4; ks++)
                acc[nt] = __builtin_amdgcn_mfma_f32_16x16x32_f16(afrag[ks], bp[ks * 4], acc[nt], 0, 0, 0);
        }
        const int orow0 = rbase + kg * 4;
        #pragma unroll
        for (int nt = 0; nt < 8; nt++) {
            const int col = nt * 16 + cl;
            const float alc = al1[col], arc = ar1[col];
            #pragma unroll
            for (int r = 0; r < 4; r++) {
                const float v = acc[nt][r];
                const int orow = orow0 + r;
                const bool ok = (orow < NN);
                if (ok) h1h[(size_t)orow * 128 + col] = __float2half(v);
                float pe = v * alc, pr = v * arc;
                #pragma unroll
                for (int m = 1; m < 16; m <<= 1) {
                    pe += __shfl_xor(pe, m, 64);
                    pr += __shfl_xor(pr, m, 64);
                }
                if (ok && cl == 0) {
                    el1[(size_t)orow * 8 + nt] = pe;
                    er1[(size_t)orow * 8 + nt] = pr;
                }
            }
        }
    }
}

// ---------------- K3: sortB — per-bucket histogram -> offs, scatter to csr ----------------
__global__ __launch_bounds__(1024) void sortB_k(const int* __restrict__ gcur,
                                                const int2* __restrict__ stage,
                                                int* __restrict__ offs,
                                                unsigned int* __restrict__ csr) {
    __shared__ int cnt[256], cur[256], gall[NBK];
    __shared__ int wsum[4];
    __shared__ int sbase;
    const int b = blockIdx.x, t = threadIdx.x;
    if (t < NBK) gall[t] = gcur[t << GPAD];
    if (t < 256) cnt[t] = 0;
    __syncthreads();
    const int nb = gall[b];
    if (t < 64) {   // wave 0: base = sum gall[0..b)
        int part = 0;
        for (int i = t; i < b; i += 64) part += gall[i];
        #pragma unroll
        for (int m = 1; m < 64; m <<= 1) part += __shfl_xor(part, m, 64);
        if (t == 0) sbase = part;
    }
    const int2* sp = stage + (size_t)b * SCAP;
    for (int i = t; i < nb; i += 1024) atomicAdd(&cnt[(sp[i].x >> 16) & BMASK], 1);
    __syncthreads();
    const int base = sbase;
    const int dlo = b << BSH;
    {   // exclusive scan of cnt[0..256) by threads 0..255
        const int lane = t & 63, wid = t >> 6;
        const int v = (t < 256) ? cnt[t] : 0;
        int s = v;
        #pragma unroll
        for (int off = 1; off < 64; off <<= 1) {
            int u = __shfl_up(s, off, 64);
            if (lane >= off) s += u;
        }
        if (t < 256 && lane == 63) wsum[wid] = s;
        __syncthreads();
        if (t < 256) {
            int add = 0;
            for (int w = 0; w < wid; w++) add += wsum[w];
            const int excl = s - v + add;
            cur[t] = excl;
            if (dlo + t < NN) offs[dlo + t] = base + excl;
        }
        if (b == NBK - 1 && t == 0) offs[NN] = base + nb;
    }
    __syncthreads();
    for (int i = t; i < nb; i += 1024) {
        const int2 pr = sp[i];
        const int dloc = (pr.x >> 16) & BMASK;
        const int sv = pr.x & 0xFFFF;
        const int r = atomicAdd(&cur[dloc], 1);
        const __half hw = __float2half(__int_as_float(pr.y));
        csr[base + r] = (unsigned int)sv | ((unsigned int)__half_as_ushort(hw) << 16);
    }
}

// ---------------- K4: Layer 1 aggregation — 32-edge tiles, csr prefetch, all-shfl ----------------
// logits: head h=l&7, eb=l>>3; lane's edges E'=eb+8k' (k'=0..3), pw kept in flat pwv[k'].
// values: dim-group g=l&15 (head hg=g>>1), es=l>>4; lane's edges E=es+4k (k=0..7).
//   pw[E][hg] lives in lane ((E&7)<<3)|hg = ((es+4*(k&1))<<3)|hg, slot E>>3 = k>>1.
__global__ __launch_bounds__(128) void agg1_k(const int* __restrict__ offs,
                                              const unsigned int* __restrict__ csr,
                                              const __half* __restrict__ h1h,
                                              const float* __restrict__ el1,
                                              const float* __restrict__ er1,
                                              const float* __restrict__ b1,
                                              __half* __restrict__ h2in_h) {
    const int t = threadIdx.x, w = t >> 6, l = t & 63;
    const int n = blockIdx.x * 2 + w;
    const int beg = offs[n], deg = offs[n + 1] - beg;
    const int h = l & 7, eb = l >> 3;
    const int g = l & 15, es = l >> 4, hg = g >> 1;
    const float er_h = er1[(size_t)n * 8 + h];
    float z_lane = 0.f;
    float acc[8];
    #pragma unroll
    for (int j = 0; j < 8; j++) acc[j] = 0.f;
    const float4* hp4 = (const float4*)h1h;

    int pr = 0;
    if (l < 32 && l < deg) pr = (int)csr[beg + l];
    for (int base = 0; base < deg; base += 32) {
        // prefetch next tile's csr
        int prn = 0;
        const int nbase = base + 32;
        if (nbase < deg && l < 32 && nbase + l < deg) prn = (int)csr[beg + nbase + l];
        // logits: this lane's 4 edges (eb+8k') at head h
        float pwv[4];
        #pragma unroll
        for (int k = 0; k < 4; k++) {
            const unsigned int pre = (unsigned int)__shfl(pr, eb + 8 * k, 64);
            float lg = -1e30f;
            if (base + eb + 8 * k < deg) {
                const float v = el1[(size_t)(pre & 0xFFFF) * 8 + h] + er_h;
                lg = v > 0.f ? v : 0.2f * v;
            }
            const float p = __expf(lg);    // 0 for padded slots
            z_lane += p;
            pwv[k] = p * __half2float(__ushort_as_half((unsigned short)(pre >> 16)));
        }
        // values: 8 edges E = es+4k
        int sv[8];
        float pp[8];
        #pragma unroll
        for (int k = 0; k < 8; k++) sv[k] = __shfl(pr, es + 4 * k, 64) & 0xFFFF;
        #pragma unroll
        for (int k = 0; k < 8; k++) {
            const int slane = ((es + 4 * (k & 1)) << 3) | hg;
            pp[k] = __shfl(pwv[k >> 1], slane, 64);
        }
        float4 vv[8];
        #pragma unroll
        for (int k = 0; k < 8; k++) vv[k] = hp4[(size_t)sv[k] * 16 + g];
        #pragma unroll
        for (int k = 0; k < 8; k++) {
            #pragma unroll
            for (int q = 0; q < 4; q++) {
                const float2 f = __half22float2(((const __half2*)&vv[k])[q]);
                acc[2 * q]     = fmaf(pp[k], f.x, acc[2 * q]);
                acc[2 * q + 1] = fmaf(pp[k], f.y, acc[2 * q + 1]);
            }
        }
        pr = prn;
    }
    // z: reduce over eb (bits 3,4,5)
    z_lane += __shfl_xor(z_lane, 8, 64);
    z_lane += __shfl_xor(z_lane, 16, 64);
    z_lane += __shfl_xor(z_lane, 32, 64);
    // acc: reduce over es (bits 4,5)
    #pragma unroll
    for (int j = 0; j < 8; j++) {
        acc[j] += __shfl_xor(acc[j], 16, 64);
        acc[j] += __shfl_xor(acc[j], 32, 64);
    }
    const float zg = __shfl(z_lane, hg, 64);   // lane hg: eb=0, h=hg
    if (l < 16) {
        const float inv = (deg > 0) ? 1.f / zg : 0.f;
        const float4* b4 = (const float4*)b1;
        const float4 bb0 = b4[g * 2], bb1 = b4[g * 2 + 1];
        __half hv[8];
        hv[0] = __float2half(fmaxf(acc[0] * inv + bb0.x, 0.f));
        hv[1] = __float2half(fmaxf(acc[1] * inv + bb0.y, 0.f));
        hv[2] = __float2half(fmaxf(acc[2] * inv + bb0.z, 0.f));
        hv[3] = __float2half(fmaxf(acc[3] * inv + bb0.w, 0.f));
        hv[4] = __float2half(fmaxf(acc[4] * inv + bb1.x, 0.f));
        hv[5] = __float2half(fmaxf(acc[5] * inv + bb1.y, 0.f));
        hv[6] = __float2half(fmaxf(acc[6] * inv + bb1.z, 0.f));
        hv[7] = __float2half(fmaxf(acc[7] * inv + bb1.w, 0.f));
        *(int4*)(h2in_h + (size_t)n * 128 + g * 8) = *(const int4*)hv;
    }
}

// ---------------- K5: Layer 2 projection (MFMA) ----------------
__global__ __launch_bounds__(256) void proj2_k(const __half* __restrict__ xh,
                                               const __half* __restrict__ w2t,
                                               const float* __restrict__ al2,
                                               const float* __restrict__ ar2,
                                               __half* __restrict__ h2h,
                                               float* __restrict__ el2,
                                               float* __restrict__ er2) {
    const int t = threadIdx.x, l = t & 63, wv = t >> 6;
    const int rbase = blockIdx.x * 64 + wv * 16;
    const int cl = l & 15, kg = l >> 4;
    const int arow = rbase + cl;
    const __half* xrow = xh + (size_t)(arow < NN ? arow : NN - 1) * 128;
    f16x8 afrag[4];
    #pragma unroll
    for (int ks = 0; ks < 4; ks++)
        afrag[ks] = *(const f16x8*)(xrow + ks * 32 + kg * 8);
    f32x4 acc[4];
    #pragma unroll
    for (int nt = 0; nt < 4; nt++) { acc[nt][0]=0.f; acc[nt][1]=0.f; acc[nt][2]=0.f; acc[nt][3]=0.f; }
    #pragma unroll
    for (int nt = 0; nt < 4; nt++) {
        const f16x8* bp = (const f16x8*)(w2t + (size_t)(nt * 16 + cl) * 128 + kg * 8);
        #pragma unroll
        for (int ks = 0; ks < 4; ks++)
            acc[nt] = __builtin_amdgcn_mfma_f32_16x16x32_f16(afrag[ks], bp[ks * 4], acc[nt], 0, 0, 0);
    }
    const int orow0 = rbase + kg * 4;
    float pe[4] = {0.f, 0.f, 0.f, 0.f}, pr[4] = {0.f, 0.f, 0.f, 0.f};
    #pragma unroll
    for (int nt = 0; nt < 4; nt++) {
        const int col = nt * 16 + cl;
        const float alc = al2[col], arc = ar2[col];
        #pragma unroll
        for (int r = 0; r < 4; r++) {
            const float v = acc[nt][r];
            const int orow = orow0 + r;
            if (orow < NN) h2h[(size_t)orow * 64 + col] = __float2half(v);
            pe[r] = fmaf(v, alc, pe[r]);
            pr[r] = fmaf(v, arc, pr[r]);
        }
    }
    #pragma unroll
    for (int r = 0; r < 4; r++) {
        #pragma unroll
        for (int m = 1; m < 16; m <<= 1) {
            pe[r] += __shfl_xor(pe[r], m, 64);
            pr[r] += __shfl_xor(pr[r], m, 64);
        }
        const int orow = orow0 + r;
        if (cl == 0 && orow < NN) { el2[orow] = pe[r]; er2[orow] = pr[r]; }
    }
}

// ---------------- K6: Layer 2 aggregation — 32-edge tiles, prefetch ----------------
// logits: lane l<32 owns edge l. values: g=l&7 (8 dims), es=l>>3 (0..7), edges es+8k (k=0..3)
__global__ __launch_bounds__(128) void agg2_k(const int* __restrict__ offs,
                                              const unsigned int* __restrict__ csr,
                                              const __half* __restrict__ h2h,
                                              const float* __restrict__ el2,
                                              const float* __restrict__ er2,
                                              const float* __restrict__ b2,
                                              float* __restrict__ out) {
    const int t = threadIdx.x, w = t >> 6, l = t & 63;
    const int n = blockIdx.x * 2 + w;
    const int beg = offs[n], deg = offs[n + 1] - beg;
    const int g = l & 7, es = l >> 3;
    const float erd = er2[n];
    float z_lane = 0.f;
    float acc[8];
    #pragma unroll
    for (int j = 0; j < 8; j++) acc[j] = 0.f;
    const float4* hp4 = (const float4*)h2h;

    int pr = 0;
    if (l < 32 && l < deg) pr = (int)csr[beg + l];
    for (int base = 0; base < deg; base += 32) {
        int prn = 0;
        const int nbase = base + 32;
        if (nbase < deg && l < 32 && nbase + l < deg) prn = (int)csr[beg + nbase + l];
        float pw = 0.f;
        if (l < 32 && base + l < deg) {
            const float v = el2[(unsigned int)pr & 0xFFFF] + erd;
            const float lg = v > 0.f ? v : 0.2f * v;
            const float p = __expf(lg);
            z_lane += p;
            pw = p * __half2float(__ushort_as_half((unsigned short)((unsigned int)pr >> 16)));
        }
        int sv[4];
        float pp[4];
        #pragma unroll
        for (int k = 0; k < 4; k++) {
            sv[k] = __shfl(pr, es + 8 * k, 64) & 0xFFFF;
            pp[k] = __shfl(pw, es + 8 * k, 64);
        }
        float4 vv[4];
        #pragma unroll
        for (int k = 0; k < 4; k++) vv[k] = hp4[(size_t)sv[k] * 8 + g];
        #pragma unroll
        for (int k = 0; k < 4; k++) {
            #pragma unroll
            for (int q = 0; q < 4; q++) {
                const float2 f = __half22float2(((const __half2*)&vv[k])[q]);
                acc[2 * q]     = fmaf(pp[k], f.x, acc[2 * q]);
                acc[2 * q + 1] = fmaf(pp[k], f.y, acc[2 * q + 1]);
            }
        }
        pr = prn;
    }
    // z: full butterfly (lanes >=32 contribute 0)
    z_lane += __shfl_xor(z_lane, 1, 64);
    z_lane += __shfl_xor(z_lane, 2, 64);
    z_lane += __shfl_xor(z_lane, 4, 64);
    z_lane += __shfl_xor(z_lane, 8, 64);
    z_lane += __shfl_xor(z_lane, 16, 64);
    z_lane += __shfl_xor(z_lane, 32, 64);
    // acc: reduce over es (bits 3,4,5)
    #pragma unroll
    for (int j = 0; j < 8; j++) {
        acc[j] += __shfl_xor(acc[j], 8, 64);
        acc[j] += __shfl_xor(acc[j], 16, 64);
        acc[j] += __shfl_xor(acc[j], 32, 64);
    }
    if (l < 8) {
        const float inv = (deg > 0) ? 1.f / z_lane : 0.f;
        const float4* b4 = (const float4*)b2;
        const float4 bb0 = b4[g * 2], bb1 = b4[g * 2 + 1];
        float4 o0, o1;
        o0.x = acc[0] * inv + bb0.x;
        o0.y = acc[1] * inv + bb0.y;
        o0.z = acc[2] * inv + bb0.z;
        o0.w = acc[3] * inv + bb0.w;
        o1.x = acc[4] * inv + bb1.x;
        o1.y = acc[5] * inv + bb1.y;
        o1.z = acc[6] * inv + bb1.z;
        o1.w = acc[7] * inv + bb1.w;
        float4* op = (float4*)(out + (size_t)n * 64 + g * 8);
        op[0] = o0; op[1] = o1;
    }
}

// ---------------- host ----------------

extern "C" void kernel_launch(void* const* d_in, const int* in_sizes, int n_in,
                              void* d_out, int out_size, void* d_ws, size_t ws_size,
                              hipStream_t stream) {
    const float* feat = (const float*)d_in[0];
    const int*   srcv = (const int*)d_in[1];
    const int*   dstv = (const int*)d_in[2];
    const float* wE   = (const float*)d_in[3];
    const float* W1   = (const float*)d_in[4];
    const float* al1  = (const float*)d_in[5];
    const float* ar1  = (const float*)d_in[6];
    const float* b1   = (const float*)d_in[7];
    const float* W2   = (const float*)d_in[8];
    const float* al2  = (const float*)d_in[9];
    const float* ar2  = (const float*)d_in[10];
    const float* b2   = (const float*)d_in[11];
    float* out = (float*)d_out;

    char* ws = (char*)d_ws;
    size_t off = 0;
    auto take = [&](size_t bytes) -> char* {
        char* pp = ws + off;
        off = (off + bytes + 255) & ~(size_t)255;
        return pp;
    };
    __half* h1h   = (__half*)take((size_t)NN * 128 * 2);
    __half* h2h   = (__half*)take((size_t)NN * 64 * 2);
    __half* h2in_h= (__half*)take((size_t)NN * 128 * 2);   // 12.8 MB; first ~8 MB aliased as sort staging
    float* el1  = (float*)take((size_t)NN * 8 * 4);
    float* er1  = (float*)take((size_t)NN * 8 * 4);
    float* el2  = (float*)take((size_t)NN * 4);
    float* er2  = (float*)take((size_t)NN * 4);
    int* offs   = (int*)take((size_t)(NN + 1) * 4);
    unsigned int* csr = (unsigned int*)take((size_t)NE * 4);
    int* gcur   = (int*)take((size_t)(NBK << GPAD) * 4);
    __half* w1t = (__half*)take((size_t)128 * 128 * 2);
    __half* w2t = (__half*)take((size_t)64 * 128 * 2);
    int2* stage = (int2*)h2in_h;   // NBK*SCAP*8 = 8.03 MB, consumed (sortB) before agg1 writes h2in_h

    init_k<<<64, 256, 0, stream>>>(W1, W2, w1t, w2t, gcur);
    sortA_proj1_k<<<NBLK_A + NBLK_P, 256, 0, stream>>>(srcv, dstv, wE, gcur, stage,
                                                       feat, w1t, al1, ar1, h1h, el1, er1);
    sortB_k<<<NBK, 1024, 0, stream>>>(gcur, stage, offs, csr);
    agg1_k<<<NN / 2, 128, 0, stream>>>(offs, csr, h1h, el1, er1, b1, h2in_h);
    proj2_k<<<(NN + 63) / 64, 256, 0, stream>>>(h2in_h, w2t, al2, ar2, h2h, el2, er2);
    agg2_k<<<NN / 2, 128, 0, stream>>>(offs, csr, h2h, el2, er2, b2, out);
}